// Round 1
// baseline (5645.518 us; speedup 1.0000x reference)
//
#include <hip/hip_runtime.h>

// GCN 3-layer, N=500000 nodes, E=8000000 edges.
// Key algebra: aggregation is linear, so aggregate BEFORE W where possible:
//   L1: (A_hat @ inp) @ W1          -> 3-dim edge aggregation
//   L2: [A_hat h1, A_hat inp] @ W2  -> 29-dim edge aggregation (A_hat inp reused)
//   L3: A_hat (h' @ W3)             -> 1-dim edge aggregation (z scalar per node)
// Normalization: dinv[d] * sum_{e: dst=d} (dinv*v)[src]  (pre/post scale, no coef array).
//
// Workspace layout (floats), N = #nodes:
//   u0   [N,4]  : {inp0*dinv, inp1*dinv, y1*dinv, dinv}   (float4 aligned)
//   deg  [N]    : uint in-degree counts
//   agg0 [N,4]  : sum of u0[src] over in-edges (3 used)
//   h1s  [N,32] : h1*dinv padded to 32 (zeros in 29..31)
//   agg1 [N,32] : sum of h1s[src]
//   zs   [N]    : z*dinv
//   acc  [N]    : sum of zs[src]
// total 75N floats = 150 MB

__global__ void deg_kernel(const int* __restrict__ dst, unsigned int* __restrict__ deg, int E) {
    int e = blockIdx.x * blockDim.x + threadIdx.x;
    if (e < E) atomicAdd(&deg[dst[e]], 1u);
}

__global__ void node1_kernel(const float* __restrict__ x, const float* __restrict__ y1,
                             const unsigned int* __restrict__ deg, float4* __restrict__ u0, int N) {
    int n = blockIdx.x * blockDim.x + threadIdx.x;
    if (n >= N) return;
    float d  = (float)deg[n] + 1.0f;   // +1 self loop
    float di = rsqrtf(d);
    u0[n] = make_float4(x[2 * n] * di, x[2 * n + 1] * di, y1[n] * di, di);
}

__global__ void edge1_kernel(const int* __restrict__ src, const int* __restrict__ dst,
                             const float4* __restrict__ u0, float* __restrict__ agg0, int E) {
    int e = blockIdx.x * blockDim.x + threadIdx.x;
    if (e >= E) return;
    int s = src[e], d = dst[e];
    float4 u = u0[s];
    atomicAdd(&agg0[4 * d + 0], u.x);
    atomicAdd(&agg0[4 * d + 1], u.y);
    atomicAdd(&agg0[4 * d + 2], u.z);
}

__global__ void node2_kernel(const float4* __restrict__ u0, const float4* __restrict__ agg0,
                             const float* __restrict__ W1, const float* __restrict__ b1,
                             float4* __restrict__ h1s, int N) {
    int n = blockIdx.x * blockDim.x + threadIdx.x;
    if (n >= N) return;
    float4 u = u0[n];
    float di = u.w;
    float4 g = agg0[n];
    // A_hat inp = agg0*di + inp*di^2 = di*(agg0 + inp*di) = di*(agg0 + u.xyz)
    float a0 = (g.x + u.x) * di, a1 = (g.y + u.y) * di, a2 = (g.z + u.z) * di;
    float h[32];
#pragma unroll
    for (int j = 0; j < 29; j++) {
        float v = fmaf(a0, W1[j], fmaf(a1, W1[29 + j], fmaf(a2, W1[58 + j], b1[j])));
        h[j] = fmaxf(v, 0.0f) * di;   // pre-scale by dinv for next aggregation
    }
    h[29] = h[30] = h[31] = 0.0f;
#pragma unroll
    for (int q = 0; q < 8; q++)
        h1s[(size_t)n * 8 + q] = make_float4(h[4 * q], h[4 * q + 1], h[4 * q + 2], h[4 * q + 3]);
}

// 8 lanes per edge; lane l handles components [4l, 4l+4). Only comps <29 are atomically added.
__global__ void edge2_kernel(const int* __restrict__ src, const int* __restrict__ dst,
                             const float4* __restrict__ h1s, float* __restrict__ agg1, int E) {
    int t = blockIdx.x * blockDim.x + threadIdx.x;   // 8E < 2^31
    int e = t >> 3;
    int l = t & 7;
    if (e >= E) return;
    int s = src[e], d = dst[e];
    float4 v = h1s[(size_t)s * 8 + l];               // 128B coalesced row gather per edge
    float* out = agg1 + (size_t)d * 32 + l * 4;
    if (l < 7) {
        atomicAdd(out + 0, v.x);
        atomicAdd(out + 1, v.y);
        atomicAdd(out + 2, v.z);
        atomicAdd(out + 3, v.w);
    } else {
        atomicAdd(out + 0, v.x);                      // component 28 only
    }
}

__global__ void node3_kernel(const float* __restrict__ x, const float* __restrict__ y1,
                             const float4* __restrict__ u0, const float4* __restrict__ agg0,
                             const float4* __restrict__ agg1, const float4* __restrict__ h1s,
                             const float* __restrict__ W2, const float* __restrict__ b2,
                             const float* __restrict__ W3, const float* __restrict__ b3,
                             float* __restrict__ zs, float* __restrict__ out, int N) {
    int n = blockIdx.x * blockDim.x + threadIdx.x;
    if (n >= N) return;
    float4 u = u0[n];
    float di = u.w;
    float g[32];
#pragma unroll
    for (int q = 0; q < 8; q++) {
        float4 A = agg1[(size_t)n * 8 + q];
        float4 H = h1s[(size_t)n * 8 + q];
        g[4 * q + 0] = (A.x + H.x) * di;   // agg1*di + h1*di^2  (h1s = h1*di)
        g[4 * q + 1] = (A.y + H.y) * di;
        g[4 * q + 2] = (A.z + H.z) * di;
        g[4 * q + 3] = (A.w + H.w) * di;
    }
    float4 G0 = agg0[n];
    g[29] = (G0.x + u.x) * di;   // A_hat inp, reused from layer 1
    g[30] = (G0.y + u.y) * di;
    g[31] = (G0.z + u.z) * di;

    float acc2[29];
#pragma unroll
    for (int k = 0; k < 29; k++) acc2[k] = b2[k];
#pragma unroll
    for (int j = 0; j < 32; j++) {
        float gj = g[j];
#pragma unroll
        for (int k = 0; k < 29; k++) acc2[k] = fmaf(gj, W2[j * 29 + k], acc2[k]);
    }
    float z = 0.0f;
#pragma unroll
    for (int k = 0; k < 29; k++) z = fmaf(fmaxf(acc2[k], 0.0f), W3[k], z);
    float inp0 = x[2 * n], inp1 = x[2 * n + 1], inp2 = y1[n];
    z = fmaf(inp0, W3[29], z);
    z = fmaf(inp1, W3[30], z);
    z = fmaf(inp2, W3[31], z);
    zs[n]  = z * di;
    out[n] = fmaf(z * di, di, b3[0]);   // self term + bias; edge sum added in node4
}

__global__ void edge3_kernel(const int* __restrict__ src, const int* __restrict__ dst,
                             const float* __restrict__ zs, float* __restrict__ acc, int E) {
    int e = blockIdx.x * blockDim.x + threadIdx.x;
    if (e >= E) return;
    atomicAdd(&acc[dst[e]], zs[src[e]]);
}

__global__ void node4_kernel(const float4* __restrict__ u0, const float* __restrict__ acc,
                             float* __restrict__ out, int N) {
    int n = blockIdx.x * blockDim.x + threadIdx.x;
    if (n >= N) return;
    out[n] += acc[n] * u0[n].w;
}

extern "C" void kernel_launch(void* const* d_in, const int* in_sizes, int n_in,
                              void* d_out, int out_size, void* d_ws, size_t ws_size,
                              hipStream_t stream) {
    const float* x  = (const float*)d_in[0];
    const float* y1 = (const float*)d_in[1];
    const int*   ei = (const int*)d_in[2];
    const float* W1 = (const float*)d_in[3];
    const float* b1 = (const float*)d_in[4];
    const float* W2 = (const float*)d_in[5];
    const float* b2 = (const float*)d_in[6];
    const float* W3 = (const float*)d_in[7];
    const float* b3 = (const float*)d_in[8];
    float* out = (float*)d_out;

    int N = in_sizes[1];
    int E = in_sizes[2] / 2;
    const int* src = ei;
    const int* dst = ei + E;

    float* ws = (float*)d_ws;
    float4*       u0   = (float4*)ws;                         // 4N floats
    unsigned int* deg  = (unsigned int*)(ws + (size_t)4 * N); // N
    float*        agg0 = ws + (size_t)5 * N;                  // 4N
    float*        h1s  = ws + (size_t)9 * N;                  // 32N
    float*        agg1 = ws + (size_t)41 * N;                 // 32N
    float*        zs   = ws + (size_t)73 * N;                 // N
    float*        acc  = ws + (size_t)74 * N;                 // N

    // zero the accumulated regions (ws is poisoned 0xAA each call)
    hipMemsetAsync(ws + (size_t)4 * N, 0, (size_t)5 * N * sizeof(float), stream);   // deg + agg0
    hipMemsetAsync(ws + (size_t)41 * N, 0, (size_t)32 * N * sizeof(float), stream); // agg1
    hipMemsetAsync(ws + (size_t)74 * N, 0, (size_t)N * sizeof(float), stream);      // acc

    const int B  = 256;
    const int gE = (E + B - 1) / B;
    const int gN = (N + B - 1) / B;
    const int gE8 = (int)(((long long)E * 8 + B - 1) / B);

    deg_kernel  <<<gE, B, 0, stream>>>(dst, deg, E);
    node1_kernel<<<gN, B, 0, stream>>>(x, y1, deg, u0, N);
    edge1_kernel<<<gE, B, 0, stream>>>(src, dst, u0, agg0, E);
    node2_kernel<<<gN, B, 0, stream>>>(u0, (const float4*)agg0, W1, b1, (float4*)h1s, N);
    edge2_kernel<<<gE8, B, 0, stream>>>(src, dst, (const float4*)h1s, agg1, E);
    node3_kernel<<<gN, B, 0, stream>>>(x, y1, u0, (const float4*)agg0, (const float4*)agg1,
                                       (const float4*)h1s, W2, b2, W3, b3, zs, out, N);
    edge3_kernel<<<gE, B, 0, stream>>>(src, dst, zs, acc, E);
    node4_kernel<<<gN, B, 0, stream>>>(u0, acc, out, N);
}

// Round 2
// 1322.827 us; speedup vs baseline: 4.2678x; 4.2678x over previous
//
#include <hip/hip_runtime.h>

// GCN 3-layer, N=500000 nodes, E=8000000 edges — CSR-pull formulation (no fp atomics).
//
// Algebra (aggregation commutes with linear maps):
//   L1: (A_hat @ inp) @ W1          -> 3-dim aggregation of u0
//   L2: [A_hat h1, A_hat inp] @ W2  -> 29-dim aggregation of h1s (A_hat inp reused)
//   L3: A_hat (h' @ W3)             -> 1-dim aggregation of zs
// Normalization factorized: A_hat v = dinv * (sum_{nbrs}(dinv*v) + dinv*v_self).
//
// Pipeline: deg histogram -> exclusive scan -> bucket-fill perm[] (CSR by dst)
//   -> pull gathers (plain stores, zero fp atomics).
//
// Workspace (4-byte units), N=500000, E=8000000, Nh=(N+1)/2:
//   u0   [N,4]    {x0*di, x1*di, y1*di, di}
//   deg  [N] u32, cursor [N] u32 (adjacent: one memset)
//   row  [N] u32  exclusive prefix of deg
//   bsum [1024] u32
//   zs   [N]
//   perm [E] i32  neighbor (src) lists grouped by dst
//   h1s  [N,32]   h1*di in 0..28, (a0,a1,a2)=A_hat·inp stashed in 29..31
//   agg1 [Nh,32]  neighbor sums for one half of the nodes (two passes)
// total = 56N + E + 1024 floats ~= 144 MB

#define CHUNK 1024  // scan: 256 threads x 4 items

__global__ void deg_kernel(const int* __restrict__ dst, unsigned int* __restrict__ deg, int E) {
    int e = blockIdx.x * blockDim.x + threadIdx.x;
    if (e < E) atomicAdd(&deg[dst[e]], 1u);
}

__global__ void node1_kernel(const float* __restrict__ x, const float* __restrict__ y1,
                             const unsigned int* __restrict__ deg, float4* __restrict__ u0, int N) {
    int n = blockIdx.x * blockDim.x + threadIdx.x;
    if (n >= N) return;
    float di = rsqrtf((float)deg[n] + 1.0f);   // +1 self loop
    u0[n] = make_float4(x[2 * n] * di, x[2 * n + 1] * di, y1[n] * di, di);
}

__global__ void scan_partial(const unsigned int* __restrict__ deg, unsigned int* __restrict__ bsum, int N) {
    __shared__ unsigned int lds[256];
    int tid = threadIdx.x;
    int base = blockIdx.x * CHUNK + tid * 4;
    unsigned int s = 0;
#pragma unroll
    for (int i = 0; i < 4; i++) if (base + i < N) s += deg[base + i];
    lds[tid] = s; __syncthreads();
    for (int off = 128; off > 0; off >>= 1) {
        if (tid < off) lds[tid] += lds[tid + off];
        __syncthreads();
    }
    if (tid == 0) bsum[blockIdx.x] = lds[0];
}

__global__ void scan_bsums(unsigned int* __restrict__ bsum, int n) {  // single block of 512
    __shared__ unsigned int lds[512];
    int tid = threadIdx.x;
    unsigned int v = (tid < n) ? bsum[tid] : 0u;
    lds[tid] = v; __syncthreads();
    for (int off = 1; off < 512; off <<= 1) {
        unsigned int t = (tid >= off) ? lds[tid - off] : 0u;
        __syncthreads();
        lds[tid] += t;
        __syncthreads();
    }
    if (tid < n) bsum[tid] = lds[tid] - v;   // exclusive
}

__global__ void scan_write(const unsigned int* __restrict__ deg, const unsigned int* __restrict__ bsum,
                           unsigned int* __restrict__ row, int N) {
    __shared__ unsigned int lds[256];
    int tid = threadIdx.x;
    int base = blockIdx.x * CHUNK + tid * 4;
    unsigned int v[4]; unsigned int s = 0;
#pragma unroll
    for (int i = 0; i < 4; i++) { v[i] = (base + i < N) ? deg[base + i] : 0u; s += v[i]; }
    lds[tid] = s; __syncthreads();
    for (int off = 1; off < 256; off <<= 1) {
        unsigned int t = (tid >= off) ? lds[tid - off] : 0u;
        __syncthreads();
        lds[tid] += t;
        __syncthreads();
    }
    unsigned int run = lds[tid] - s + bsum[blockIdx.x];
#pragma unroll
    for (int i = 0; i < 4; i++) {
        if (base + i < N) { row[base + i] = run; run += v[i]; }
    }
}

__global__ void build_kernel(const int* __restrict__ src, const int* __restrict__ dst,
                             const unsigned int* __restrict__ row, unsigned int* __restrict__ cursor,
                             int* __restrict__ perm, int E) {
    int e = blockIdx.x * blockDim.x + threadIdx.x;
    if (e >= E) return;
    int d = dst[e];
    unsigned int pos = row[d] + atomicAdd(&cursor[d], 1u);
    perm[pos] = src[e];
}

// Fused: layer-1 pull + W1 matmul + relu. One thread per node.
__global__ void layer1_kernel(const float4* __restrict__ u0, const unsigned int* __restrict__ row,
                              const unsigned int* __restrict__ deg, const int* __restrict__ perm,
                              const float* __restrict__ W1, const float* __restrict__ b1,
                              float4* __restrict__ h1s, int N) {
    int n = blockIdx.x * blockDim.x + threadIdx.x;
    if (n >= N) return;
    float4 u = u0[n];
    float di = u.w;
    float sx = u.x, sy = u.y, sz = u.z;        // self term (u0 = inp*di)
    unsigned int j = row[n], e0 = j + deg[n];
    for (; j < e0; j++) {
        float4 v = u0[perm[j]];
        sx += v.x; sy += v.y; sz += v.z;
    }
    float a0 = sx * di, a1 = sy * di, a2 = sz * di;   // A_hat inp
    float h[32];
#pragma unroll
    for (int k = 0; k < 29; k++) {
        float v = fmaf(a0, W1[k], fmaf(a1, W1[29 + k], fmaf(a2, W1[58 + k], b1[k])));
        h[k] = fmaxf(v, 0.0f) * di;            // pre-scale for next aggregation
    }
    h[29] = a0; h[30] = a1; h[31] = a2;        // stash A_hat inp in pad slots
    size_t base = (size_t)n * 8;
#pragma unroll
    for (int q = 0; q < 8; q++)
        h1s[base + q] = make_float4(h[4 * q], h[4 * q + 1], h[4 * q + 2], h[4 * q + 3]);
}

// Layer-2 pull, nodes [n0,n1): 8 threads per node, each owns one float4 of the row.
// Each neighbor row = one 128B coalesced transaction (h1s LLC-resident).
__global__ void pull2_kernel(const float4* __restrict__ h1s, const unsigned int* __restrict__ row,
                             const unsigned int* __restrict__ deg, const int* __restrict__ perm,
                             float4* __restrict__ agg1, int n0, int n1) {
    int t = blockIdx.x * blockDim.x + threadIdx.x;
    int n = n0 + (t >> 3);
    int q = t & 7;
    if (n >= n1) return;
    float4 acc = make_float4(0.f, 0.f, 0.f, 0.f);
    unsigned int j = row[n], e0 = j + deg[n];
    for (; j < e0; j++) {
        float4 v = h1s[(size_t)perm[j] * 8 + q];
        acc.x += v.x; acc.y += v.y; acc.z += v.z; acc.w += v.w;
    }
    agg1[(size_t)(n - n0) * 8 + q] = acc;
}

// Layers 2+3 node math for nodes [n0,n1): W2 matmul + relu + W3 dot. Writes zs, partial out.
__global__ void node3_kernel(const float* __restrict__ x, const float* __restrict__ y1,
                             const float4* __restrict__ u0, const float4* __restrict__ agg1,
                             const float4* __restrict__ h1s,
                             const float* __restrict__ W2, const float* __restrict__ b2,
                             const float* __restrict__ W3, const float* __restrict__ b3,
                             float* __restrict__ zs, float* __restrict__ out, int n0, int n1) {
    int n = n0 + blockIdx.x * blockDim.x + threadIdx.x;
    if (n >= n1) return;
    float di = u0[n].w;
    float g[32];
    float4 H7;
#pragma unroll
    for (int q = 0; q < 8; q++) {
        float4 A = agg1[(size_t)(n - n0) * 8 + q];
        float4 H = h1s[(size_t)n * 8 + q];
        if (q == 7) H7 = H;
        g[4 * q + 0] = (A.x + H.x) * di;   // di*(sum_nbr + self): h1s = h1*di
        g[4 * q + 1] = (A.y + H.y) * di;
        g[4 * q + 2] = (A.z + H.z) * di;
        g[4 * q + 3] = (A.w + H.w) * di;
    }
    g[29] = H7.y; g[30] = H7.z; g[31] = H7.w;   // A_hat inp, stashed by layer1

    float acc2[29];
#pragma unroll
    for (int k = 0; k < 29; k++) acc2[k] = b2[k];
#pragma unroll
    for (int j = 0; j < 32; j++) {
        float gj = g[j];
#pragma unroll
        for (int k = 0; k < 29; k++) acc2[k] = fmaf(gj, W2[j * 29 + k], acc2[k]);
    }
    float z = 0.0f;
#pragma unroll
    for (int k = 0; k < 29; k++) z = fmaf(fmaxf(acc2[k], 0.0f), W3[k], z);
    z = fmaf(x[2 * n], W3[29], z);
    z = fmaf(x[2 * n + 1], W3[30], z);
    z = fmaf(y1[n], W3[31], z);
    zs[n]  = z * di;
    out[n] = fmaf(z * di, di, b3[0]);   // self term + bias; neighbor sum added by pull3
}

// Fused: layer-3 pull + final scale. One thread per node.
__global__ void pull3_kernel(const float* __restrict__ zs, const float4* __restrict__ u0,
                             const unsigned int* __restrict__ row, const unsigned int* __restrict__ deg,
                             const int* __restrict__ perm, float* __restrict__ out, int N) {
    int n = blockIdx.x * blockDim.x + threadIdx.x;
    if (n >= N) return;
    float s = 0.0f;
    unsigned int j = row[n], e0 = j + deg[n];
    for (; j < e0; j++) s += zs[perm[j]];
    out[n] += s * u0[n].w;
}

extern "C" void kernel_launch(void* const* d_in, const int* in_sizes, int n_in,
                              void* d_out, int out_size, void* d_ws, size_t ws_size,
                              hipStream_t stream) {
    const float* x  = (const float*)d_in[0];
    const float* y1 = (const float*)d_in[1];
    const int*   ei = (const int*)d_in[2];
    const float* W1 = (const float*)d_in[3];
    const float* b1 = (const float*)d_in[4];
    const float* W2 = (const float*)d_in[5];
    const float* b2 = (const float*)d_in[6];
    const float* W3 = (const float*)d_in[7];
    const float* b3 = (const float*)d_in[8];
    float* out = (float*)d_out;

    int N = in_sizes[1];
    int E = in_sizes[2] / 2;
    const int* src = ei;
    const int* dst = ei + E;

    size_t Ns = (size_t)N;
    int Nh = (N + 1) / 2;      // node-half for agg1 tiling (peak ws = 56N + E + 1024 floats)

    float* ws = (float*)d_ws;
    float4*       u0     = (float4*)ws;                            // 4N
    unsigned int* deg    = (unsigned int*)(ws + 4 * Ns);           // N
    unsigned int* cursor = (unsigned int*)(ws + 5 * Ns);           // N (adjacent to deg: one memset)
    unsigned int* row    = (unsigned int*)(ws + 6 * Ns);           // N
    unsigned int* bsum   = (unsigned int*)(ws + 7 * Ns);           // 1024
    float*        zs     = ws + 7 * Ns + 1024;                     // N
    int*          perm   = (int*)(ws + 8 * Ns + 1024);             // E
    float4*       h1s    = (float4*)(ws + 8 * Ns + 1024 + (size_t)E);  // 32N
    float4*       agg1   = (float4*)(ws + 40 * Ns + 1024 + (size_t)E); // 32*Nh

    hipMemsetAsync(deg, 0, 2 * Ns * sizeof(unsigned int), stream);  // deg + cursor

    const int B = 256;
    const int gE = (E + B - 1) / B;
    const int gN = (N + B - 1) / B;
    const int nchunks = (N + CHUNK - 1) / CHUNK;   // 489 (<512)

    deg_kernel  <<<gE, B, 0, stream>>>(dst, deg, E);
    node1_kernel<<<gN, B, 0, stream>>>(x, y1, deg, u0, N);
    scan_partial<<<nchunks, B, 0, stream>>>(deg, bsum, N);
    scan_bsums  <<<1, 512, 0, stream>>>(bsum, nchunks);
    scan_write  <<<nchunks, B, 0, stream>>>(deg, bsum, row, N);
    build_kernel<<<gE, B, 0, stream>>>(src, dst, row, cursor, perm, E);
    layer1_kernel<<<gN, B, 0, stream>>>(u0, row, deg, perm, W1, b1, h1s, N);

    for (int half = 0; half < 2; half++) {
        int n0 = half * Nh;
        int n1 = (half == 0) ? Nh : N;
        int cnt = n1 - n0;
        int g8 = (8 * cnt + B - 1) / B;
        int gH = (cnt + B - 1) / B;
        pull2_kernel<<<g8, B, 0, stream>>>(h1s, row, deg, perm, agg1, n0, n1);
        node3_kernel<<<gH, B, 0, stream>>>(x, y1, u0, agg1, h1s, W2, b2, W3, b3,
                                           zs, out, n0, n1);
    }
    pull3_kernel<<<gN, B, 0, stream>>>(zs, u0, row, deg, perm, out, N);
}